// Round 11
// baseline (201.724 us; speedup 1.0000x reference)
//
#include <hip/hip_runtime.h>
#include <hip/hip_bf16.h>

#define NATOM 128
#define NB    127
#define D0    25
#define D1    50
#define D2    100
#define H0STR 40     // halves; 80 B rows -> b128 A-frag reads 2-way (free)
#define H1STR 56     // halves; 112 B rows; cols 51..55 pad, col 50 = 1.0 (bias)
#define MROWS 128    // DENSE rows: 127 real + 1 pad row (no per-type alignment)
#define W1H_HALVES (16 * 50 * 32)     // 25600  (K 25 -> 32; col 25 = CT*b1)
#define W2H_HALVES (16 * 100 * 64)    // 102400 (K 50 -> 64; col 50 = CT*b2)
#define WS_DWORDS  ((W1H_HALVES + W2H_HALVES) / 2)   // 64000 dwords of fp16
#define W0C_FLOATS 800                // 16*25 float2 {CT*w0, CT*b0}
#define CT 2.8853900817779268f        // 2*log2(e); tanh(x)=1-2/(exp2(CT*x)+1)

typedef _Float16 half8 __attribute__((ext_vector_type(8)));  // 8 fp16 = 4 VGPRs
typedef _Float16 half4v __attribute__((ext_vector_type(4))); // 4 fp16 = 2 VGPRs
typedef _Float16 half2v __attribute__((ext_vector_type(2))); // 2 fp16 = 1 VGPR
typedef __attribute__((ext_vector_type(4))) float f32x4;

__device__ __forceinline__ float exp2_hw(float x) {
#if defined(__has_builtin)
#if __has_builtin(__builtin_amdgcn_exp2f)
    return __builtin_amdgcn_exp2f(x);        // raw v_exp_f32 (exp2 semantics)
#else
    return __expf(0.6931471805599453f * x);
#endif
#else
    return __expf(0.6931471805599453f * x);
#endif
}

// tanh(x) with PRE-SCALED argument y = CT*x (CT folded into weights/bias):
// tanh(x) = 1 - 2/(exp2(y)+1). exp2->add->rcp->fma.
__device__ __forceinline__ float tanh_pre(float y) {
    float e = exp2_hw(y);
    return 1.0f - 2.0f * __builtin_amdgcn_rcpf(e + 1.0f);
}

// Two f32 -> packed 2xf16 in ONE instruction (v_cvt_pkrtz_f16_f32).
__device__ __forceinline__ half2v pk_f16(float a, float b) {
#if defined(__has_builtin)
#if __has_builtin(__builtin_amdgcn_cvt_pkrtz)
    return __builtin_bit_cast(half2v, __builtin_amdgcn_cvt_pkrtz(a, b));
#else
    half2v r; r[0] = (_Float16)a; r[1] = (_Float16)b; return r;
#endif
#else
    half2v r; r[0] = (_Float16)a; r[1] = (_Float16)b; return r;
#endif
}

struct F3 { float x, y, z; };   // one dwordx3 load (4B-aligned)

// ---- one-shot (per launch) weight repack into d_ws ----------------------
__global__ void cvt_kernel(const float* __restrict__ W0,
                           const float* __restrict__ B0,
                           const float* __restrict__ W1,
                           const float* __restrict__ B1,
                           const float* __restrict__ W2,
                           const float* __restrict__ B2,
                           unsigned int* __restrict__ ws) {
    const int i = blockIdx.x * 256 + threadIdx.x;   // dword index
    if (i >= WS_DWORDS + W0C_FLOATS) return;
    if (i >= WS_DWORDS) {                           // layer-0 float2 table
        const int j = i - WS_DWORDS;                // 0..799
        const int p = j >> 1;                       // idx*25+o
        const float v = (j & 1) ? B0[p] : W0[p];
        reinterpret_cast<float*>(ws)[i] = CT * v;
        return;
    }
    float v0, v1;
    if (i < W1H_HALVES / 2) {
        const int s = 2 * i;
        const int row = s >> 5, kk = s & 31;        // row = idx*50 + o
        const float* base = W1 + row * D0;
        v0 = (kk < D0) ? base[kk] : ((kk == D0) ? B1[row] : 0.f);
        v1 = (kk + 1 < D0) ? base[kk + 1] : ((kk + 1 == D0) ? B1[row] : 0.f);
    } else {
        const int s = 2 * i - W1H_HALVES;
        const int row = s >> 6, kk = s & 63;        // row = idx*100 + o
        const float* base = W2 + row * D1;
        v0 = (kk < D1) ? base[kk] : ((kk == D1) ? B2[row] : 0.f);
        v1 = (kk + 1 < D1) ? base[kk + 1] : ((kk + 1 == D1) ? B2[row] : 0.f);
    }
    union { _Float16 h[2]; unsigned int u; } cv;
    cv.h[0] = (_Float16)(CT * v0);                  // RNE, range-safe
    cv.h[1] = (_Float16)(CT * v1);
    ws[i] = cv.u;
}

__global__ __launch_bounds__(256, 1) void feat_kernel(
    const float* __restrict__ coords,
    const int*   __restrict__ types,
    const float2* __restrict__ W0c,
    const _Float16* __restrict__ W1h, const _Float16* __restrict__ W2h,
    float* __restrict__ out)
{
    // 14336 + 10240 + 768 + 624 + 32 = 25.9 KB -> up to 6 blocks/CU by LDS
    __shared__ __attribute__((aligned(16))) _Float16 H1f[MROWS][H1STR];
    __shared__ union __attribute__((aligned(16))) {
        _Float16 H0f[MROWS][H0STR];
        float    Ms[3][112];
    } u;
    __shared__ __attribute__((aligned(16))) _Float16 Eph[3][MROWS];
    __shared__ float Rt[3][52];
    __shared__ int cnt[2][4];           // per-wave type counts (waves 0,1)

    const int bn = blockIdx.x;    // b*128 + n
    const int b  = bn >> 7;
    const int n  = bn & 127;
    const int k  = threadIdx.x;   // 0..255
    const int wv = k >> 6;        // wave 0..3
    const int lq = (k >> 4) & 3;  // quad within wave
    const int ln = k & 15;
    const int lane = k & 63;
    const int tn  = types[n];

    // ---- ballot-based type counts + stable ranks (waves {0,2},{1,3} mirror)
    int tj = -1, j0 = 0, jj = -1;
    if (k < NB) jj = k;
    else if (k >= 128 && k < 128 + NB) jj = k - 128;
    if (jj >= 0) { j0 = jj + (jj >= n ? 1 : 0); tj = types[j0]; }
    const unsigned long long bm0 = __ballot(tj == 0);
    const unsigned long long bm1 = __ballot(tj == 1);
    const unsigned long long bm2 = __ballot(tj == 2);
    const unsigned long long bm3 = __ballot(tj == 3);
    if (lane == 0 && wv < 2) {
        cnt[wv][0] = __popcll(bm0); cnt[wv][1] = __popcll(bm1);
        cnt[wv][2] = __popcll(bm2); cnt[wv][3] = __popcll(bm3);
    }
    int sameBefore = 0;
    if (jj >= 0) {
        const unsigned long long mym =
            (tj == 0) ? bm0 : (tj == 1) ? bm1 : (tj == 2) ? bm2 : bm3;
        sameBefore = __popcll(mym & ((1ULL << lane) - 1ULL));
    }
    __syncthreads();

    const int c0 = cnt[0][0] + cnt[1][0];
    const int c1 = cnt[0][1] + cnt[1][1];
    const int c2 = cnt[0][2] + cnt[1][2];
    // DENSE prefix sums (no 16-alignment). P4 = 128 (row 127 = zeroed pad).
    const int P1 = c0;
    const int P2 = c0 + c1;
    const int P3 = c0 + c1 + c2;

    // ======== phase 1: geometry + layer 0, split across ALL 256 threads ====
    if (jj >= 0) {
        const int idx = (tn << 2) | tj;
        const int pst = (tj == 0) ? 0 : (tj == 1) ? P1 : (tj == 2) ? P2 : P3;
        const int pr  = pst + sameBefore + ((wv & 1) ? cnt[0][tj] : 0);

        const float cx = coords[(b * NATOM + n) * 3 + 0];
        const float cy = coords[(b * NATOM + n) * 3 + 1];
        const float cz = coords[(b * NATOM + n) * 3 + 2];
        const F3 cj = *reinterpret_cast<const F3*>(&coords[(b * NATOM + j0) * 3]);
        const float dx = cx - cj.x;
        const float dy = cy - cj.y;
        const float dz = cz - cj.z;
        const float d2   = dx * dx + dy * dy + dz * dz;
        const float inv  = rsqrtf(d2);         // 1/d (= env_r)
        const float inv2 = inv * inv;

        const float2* wb = W0c + idx * D0;     // {CT*w, CT*b} pairs
        uint2* dst2 = (uint2*)&u.H0f[pr][0];

        if (k < 128) {                         // A-half: Eph planes + h0[0..11]
            Eph[0][pr] = (_Float16)(dx * inv2);
            Eph[1][pr] = (_Float16)(dy * inv2);
            Eph[2][pr] = (_Float16)(dz * inv2);
            unsigned int dv[6];
            #pragma unroll
            for (int o = 0; o < 12; o += 2) {
                const float2 wc0 = wb[o];
                const float2 wc1 = wb[o + 1];
                union { half2v h; unsigned int v; } cv;
                cv.h = pk_f16(tanh_pre(fmaf(wc0.x, inv, wc0.y)),
                              tanh_pre(fmaf(wc1.x, inv, wc1.y)));
                dv[o >> 1] = cv.v;
            }
            uint2 s0; s0.x = dv[0]; s0.y = dv[1]; dst2[0] = s0;
            uint2 s1; s1.x = dv[2]; s1.y = dv[3]; dst2[1] = s1;
            uint2 s2; s2.x = dv[4]; s2.y = dv[5]; dst2[2] = s2;
        } else {                               // B-half: h0[12..24] + bias + pad
            unsigned int dv[7];
            #pragma unroll
            for (int q = 0; q < 6; ++q) {      // cols 12..23
                const float2 wc0 = wb[12 + 2 * q];
                const float2 wc1 = wb[13 + 2 * q];
                union { half2v h; unsigned int v; } cv;
                cv.h = pk_f16(tanh_pre(fmaf(wc0.x, inv, wc0.y)),
                              tanh_pre(fmaf(wc1.x, inv, wc1.y)));
                dv[q] = cv.v;
            }
            { const float2 wc = wb[24];        // col 24 + bias-1.0 @ col 25
              union { half2v h; unsigned int v; } cl;
              cl.h = pk_f16(tanh_pre(fmaf(wc.x, inv, wc.y)), 1.0f);
              dv[6] = cl.v; }
            uint2 s3; s3.x = dv[0]; s3.y = dv[1]; dst2[3] = s3;
            uint2 s4; s4.x = dv[2]; s4.y = dv[3]; dst2[4] = s4;
            uint2 s5; s5.x = dv[4]; s5.y = dv[5]; dst2[5] = s5;
            uint2 s6; s6.x = dv[6]; s6.y = 0u;   dst2[6] = s6;   // cols 24..27
            uint2 s7; s7.x = 0u;    s7.y = 0u;   dst2[7] = s7;   // cols 28..31
        }
    }
    // ---- single pad row (127): zero H0f K-range + Eph (E=0 masks all sums)
    if (k == 255) {
        uint2* pz = (uint2*)&u.H0f[MROWS - 1][0];
        const uint2 z2 = {0u, 0u};
        #pragma unroll
        for (int q = 0; q < 8; ++q) pz[q] = z2;
        Eph[0][MROWS - 1] = (_Float16)0.f;
        Eph[1][MROWS - 1] = (_Float16)0.f;
        Eph[2][MROWS - 1] = (_Float16)0.f;
    }
    __syncthreads();

    // Boundary-tile list: tiles containing a type boundary strictly inside.
    // P1<=P2<=P3 -> sorted; dedup adjacent. <=3 tiles; all other tiles are
    // fully inside one type.
    int bts[3]; int nbt = 0;
    if (P1 & 15) bts[nbt++] = P1 >> 4;
    if ((P2 & 15) && (nbt == 0 || bts[nbt - 1] != (P2 >> 4))) bts[nbt++] = P2 >> 4;
    if ((P3 & 15) && (nbt == 0 || bts[nbt - 1] != (P3 >> 4))) bts[nbt++] = P3 >> 4;

    // ======== phase 2a: layer 1 via MFMA (25+bias -> 50), dense rows =======
    {
        const int o1   = wv * 16 + ln;         // 0..63
        const bool ov1 = (o1 < D1);
        const bool st1 = (o1 < H1STR);         // only cols 0..55 exist
        const int o1c  = ov1 ? o1 : 0;
        const int rres1 = ((o1 < D0) ? o1 : (o1 - D0)) & 31;
        const _Float16 padv = (o1 == D1) ? (_Float16)1.0f : (_Float16)0.f;
        const int cpl = (ln < 3) ? ln : 2;
        f32x4 d2r = {0.f, 0.f, 0.f, 0.f};      // R accumulator (rows = c)

        auto epi2a = [&](int mb, f32x4 d) {
            const int mq = mb + lq * 4;
            const half4v ea = *(const half4v*)&Eph[cpl][mq];
            half2v t01 = pk_f16(tanh_pre(d[0]), tanh_pre(d[1]));
            half2v t23 = pk_f16(tanh_pre(d[2]), tanh_pre(d[3]));
            half2v q01; q01[0] = u.H0f[mq + 0][rres1];
                        q01[1] = u.H0f[mq + 1][rres1];
            half2v q23; q23[0] = u.H0f[mq + 2][rres1];
                        q23[1] = u.H0f[mq + 3][rres1];
            t01 = t01 + q01;               // v_pk_add_f16
            t23 = t23 + q23;
            half4v gb;
            gb[0] = t01[0]; gb[1] = t01[1];
            gb[2] = t23[0]; gb[3] = t23[1];
            if (st1) {
                H1f[mq + 0][o1] = ov1 ? t01[0] : padv;
                H1f[mq + 1][o1] = ov1 ? t01[1] : padv;
                H1f[mq + 2][o1] = ov1 ? t23[0] : padv;
                H1f[mq + 3][o1] = ov1 ? t23[1] : padv;
            }
            d2r = __builtin_amdgcn_mfma_f32_16x16x16f16(ea, gb, d2r, 0, 0, 0);
        };

        // full tiles, per type (bf hoisted)
        #pragma unroll
        for (int t = 0; t < 4; ++t) {
            const int lo = (t == 0) ? 0 : (t == 1) ? P1 : (t == 2) ? P2 : P3;
            const int hi = (t == 0) ? P1 : (t == 1) ? P2 : (t == 2) ? P3 : MROWS;
            const int mtLo = (lo + 15) >> 4, mtHi = hi >> 4;
            if (mtLo >= mtHi) continue;
            const int idx = (tn << 2) | t;
            const half8 bf =
                *(const half8*)(W1h + (idx * 50 + o1c) * 32 + lq * 8);
            for (int mt = mtLo; mt < mtHi; ++mt) {
                const int mb = mt * 16;
                const half8 af = *(const half8*)(&u.H0f[mb + ln][lq * 8]);
                f32x4 d = {0.f, 0.f, 0.f, 0.f};        // bias rides K-col 25
                d = __builtin_amdgcn_mfma_f32_16x16x32_f16(af, bf, d, 0, 0, 0);
                epi2a(mb, d);
            }
        }
        // boundary tiles: per overlapping type, mask A-rows to that type.
        // Masked-out rows lose col25 too -> no bias pollution; each row gets
        // exactly its own type's weights+bias across the chained MFMAs.
        for (int bi = 0; bi < nbt; ++bi) {
            const int mb = bts[bi] * 16;
            const int row = mb + ln;
            const half8 af = *(const half8*)(&u.H0f[row][lq * 8]);
            const half8 zf = {};
            f32x4 d = {0.f, 0.f, 0.f, 0.f};
            #pragma unroll
            for (int t = 0; t < 4; ++t) {
                const int lo = (t == 0) ? 0 : (t == 1) ? P1 : (t == 2) ? P2 : P3;
                const int hi = (t == 0) ? P1 : (t == 1) ? P2 : (t == 2) ? P3 : MROWS;
                if (lo >= mb + 16 || hi <= mb || lo == hi) continue;
                const int idx = (tn << 2) | t;
                const half8 bf =
                    *(const half8*)(W1h + (idx * 50 + o1c) * 32 + lq * 8);
                const bool in = (lo <= row) && (row < hi);
                const half8 afm = in ? af : zf;
                d = __builtin_amdgcn_mfma_f32_16x16x32_f16(afm, bf, d, 0, 0, 0);
            }
            epi2a(mb, d);
        }

        if (lq == 0 && o1 < D1) {
            Rt[0][o1] = d2r[0]; Rt[1][o1] = d2r[1]; Rt[2][o1] = d2r[2];
        }
    }
    __syncthreads();
    // ---- from here on, u is Ms; H0f is dead (all reads were pre-barrier)

    // ======== phase 2b: layer 2 via MFMA (50+bias -> 100) + MFMA M-reduce ==
    {
        const bool has1 = (wv < 3);             // group wv+4 exists (4..6)
        const int oA  = wv * 16 + ln;
        const int oB  = (wv + 4) * 16 + ln;
        const int ocB = (oB < D2) ? oB : (D2 - 1);
        const int rrA = (oA >= D1) ? (oA - D1) : oA;
        const int rrB = (ocB >= D1) ? (ocB - D1) : ocB;
        const int off1 = (lq == 3) ? 32 : (32 + lq * 8); // lq=3 K-rows of W2h=0
        const int cpl = (ln < 3) ? ln : 2;
        f32x4 d2A = {0.f, 0.f, 0.f, 0.f};
        f32x4 d2B = {0.f, 0.f, 0.f, 0.f};

        auto epi2b = [&](int mb, f32x4 dA, f32x4 dB) {
            const int mq = mb + lq * 4;
            const half4v ea = *(const half4v*)&Eph[cpl][mq];
            half2v a01 = pk_f16(tanh_pre(dA[0]), tanh_pre(dA[1]));
            half2v a23 = pk_f16(tanh_pre(dA[2]), tanh_pre(dA[3]));
            half4v ga;
            ga[0] = a01[0]; ga[1] = a01[1];
            ga[2] = a23[0]; ga[3] = a23[1];
            d2A = __builtin_amdgcn_mfma_f32_16x16x16f16(ea, ga, d2A, 0, 0, 0);
            if (has1) {
                half2v b01 = pk_f16(tanh_pre(dB[0]), tanh_pre(dB[1]));
                half2v b23 = pk_f16(tanh_pre(dB[2]), tanh_pre(dB[3]));
                half4v gb2;
                gb2[0] = b01[0]; gb2[1] = b01[1];
                gb2[2] = b23[0]; gb2[3] = b23[1];
                d2B = __builtin_amdgcn_mfma_f32_16x16x16f16(ea, gb2, d2B, 0, 0, 0);
            }
        };

        // full tiles, per type (bf hoisted)
        #pragma unroll
        for (int t = 0; t < 4; ++t) {
            const int lo = (t == 0) ? 0 : (t == 1) ? P1 : (t == 2) ? P2 : P3;
            const int hi = (t == 0) ? P1 : (t == 1) ? P2 : (t == 2) ? P3 : MROWS;
            const int mtLo = (lo + 15) >> 4, mtHi = hi >> 4;
            if (mtLo >= mtHi) continue;
            const int idx = (tn << 2) | t;
            const _Float16* wrA = W2h + (idx * 100 + oA) * 64;
            const half8 bfA0 = *(const half8*)(wrA + lq * 8);
            const half8 bfA1 = *(const half8*)(wrA + 32 + lq * 8);
            const _Float16* wrB = W2h + (idx * 100 + ocB) * 64;
            const half8 bfB0 = *(const half8*)(wrB + lq * 8);
            const half8 bfB1 = *(const half8*)(wrB + 32 + lq * 8);
            for (int mt = mtLo; mt < mtHi; ++mt) {
                const int mb = mt * 16;
                const _Float16* arow = &H1f[mb + ln][0];
                const half8 af0 = *(const half8*)(arow + lq * 8);
                const half8 af1 = *(const half8*)(arow + off1);
                f32x4 dA = {0.f, 0.f, 0.f, 0.f};   // bias rides K-col 50
                dA = __builtin_amdgcn_mfma_f32_16x16x32_f16(af0, bfA0, dA, 0, 0, 0);
                dA = __builtin_amdgcn_mfma_f32_16x16x32_f16(af1, bfA1, dA, 0, 0, 0);
                f32x4 dB = {0.f, 0.f, 0.f, 0.f};
                if (has1) {
                    dB = __builtin_amdgcn_mfma_f32_16x16x32_f16(af0, bfB0, dB, 0, 0, 0);
                    dB = __builtin_amdgcn_mfma_f32_16x16x32_f16(af1, bfB1, dB, 0, 0, 0);
                }
                epi2b(mb, dA, dB);
            }
        }
        // boundary tiles: masked per-type accumulation (A-frags shared)
        for (int bi = 0; bi < nbt; ++bi) {
            const int mb = bts[bi] * 16;
            const int row = mb + ln;
            const _Float16* arow = &H1f[row][0];
            const half8 af0 = *(const half8*)(arow + lq * 8);
            const half8 af1 = *(const half8*)(arow + off1);
            const half8 zf = {};
            f32x4 dA = {0.f, 0.f, 0.f, 0.f};
            f32x4 dB = {0.f, 0.f, 0.f, 0.f};
            #pragma unroll
            for (int t = 0; t < 4; ++t) {
                const int lo = (t == 0) ? 0 : (t == 1) ? P1 : (t == 2) ? P2 : P3;
                const int hi = (t == 0) ? P1 : (t == 1) ? P2 : (t == 2) ? P3 : MROWS;
                if (lo >= mb + 16 || hi <= mb || lo == hi) continue;
                const bool in = (lo <= row) && (row < hi);
                const half8 af0m = in ? af0 : zf;
                const half8 af1m = in ? af1 : zf;
                const int idx = (tn << 2) | t;
                const _Float16* wrA = W2h + (idx * 100 + oA) * 64;
                const half8 bfA0 = *(const half8*)(wrA + lq * 8);
                const half8 bfA1 = *(const half8*)(wrA + 32 + lq * 8);
                dA = __builtin_amdgcn_mfma_f32_16x16x32_f16(af0m, bfA0, dA, 0, 0, 0);
                dA = __builtin_amdgcn_mfma_f32_16x16x32_f16(af1m, bfA1, dA, 0, 0, 0);
                if (has1) {
                    const _Float16* wrB = W2h + (idx * 100 + ocB) * 64;
                    const half8 bfB0 = *(const half8*)(wrB + lq * 8);
                    const half8 bfB1 = *(const half8*)(wrB + 32 + lq * 8);
                    dB = __builtin_amdgcn_mfma_f32_16x16x32_f16(af0m, bfB0, dB, 0, 0, 0);
                    dB = __builtin_amdgcn_mfma_f32_16x16x32_f16(af1m, bfB1, dB, 0, 0, 0);
                }
            }
            epi2b(mb, dA, dB);
        }

        // D2 rows 0..2 (= c) live in lq==0 lanes; residual added via Rt.
        if (lq == 0) {
            u.Ms[0][oA] = d2A[0] + Rt[0][rrA];
            u.Ms[1][oA] = d2A[1] + Rt[1][rrA];
            u.Ms[2][oA] = d2A[2] + Rt[2][rrA];
            if (has1 && oB < D2) {
                u.Ms[0][oB] = d2B[0] + Rt[0][rrB];
                u.Ms[1][oB] = d2B[1] + Rt[1][rrB];
                u.Ms[2][oB] = d2B[2] + Rt[2][rrB];
            }
        }
    }
    __syncthreads();

    // ======== phase 3: out[m][a] = sum_c M[c][m] * M[c][a], a < 4 ==========
    if (k < D2) {
        const float m0 = u.Ms[0][k], m1 = u.Ms[1][k], m2 = u.Ms[2][k];
        float4 o4;
        o4.x = m0 * u.Ms[0][0] + m1 * u.Ms[1][0] + m2 * u.Ms[2][0];
        o4.y = m0 * u.Ms[0][1] + m1 * u.Ms[1][1] + m2 * u.Ms[2][1];
        o4.z = m0 * u.Ms[0][2] + m1 * u.Ms[1][2] + m2 * u.Ms[2][2];
        o4.w = m0 * u.Ms[0][3] + m1 * u.Ms[1][3] + m2 * u.Ms[2][3];
        reinterpret_cast<float4*>(out)[bn * D2 + k] = o4;   // 16B-aligned
    }
}

extern "C" void kernel_launch(void* const* d_in, const int* in_sizes, int n_in,
                              void* d_out, int out_size, void* d_ws, size_t ws_size,
                              hipStream_t stream) {
    (void)in_sizes; (void)n_in; (void)out_size; (void)ws_size;
    const float* coords = (const float*)d_in[0];
    const int*   types  = (const int*)  d_in[1];
    const float* W0 = (const float*)d_in[2];
    const float* B0 = (const float*)d_in[3];
    const float* W1 = (const float*)d_in[4];
    const float* B1 = (const float*)d_in[5];
    const float* W2 = (const float*)d_in[6];
    const float* B2 = (const float*)d_in[7];
    float* out = (float*)d_out;

    unsigned int* ws_u = (unsigned int*)d_ws;
    _Float16* W1h = (_Float16*)d_ws;                 // 25600 halves (CT-scaled)
    _Float16* W2h = (_Float16*)d_ws + W1H_HALVES;    // 102400 halves (CT-scaled)
    const float2* W0c = (const float2*)(ws_u + WS_DWORDS);  // 400 float2

    const int total = WS_DWORDS + W0C_FLOATS;        // 64800 dwords
    cvt_kernel<<<(total + 255) / 256, 256, 0, stream>>>(
        W0, B0, W1, B1, W2, B2, ws_u);

    feat_kernel<<<64 * NATOM, 256, 0, stream>>>(
        coords, types, W0c, W1h, W2h, out);
}

// Round 12
// 160.503 us; speedup vs baseline: 1.2568x; 1.2568x over previous
//
#include <hip/hip_runtime.h>
#include <hip/hip_bf16.h>

#define NATOM 128
#define NB    127
#define D0    25
#define D1    50
#define D2    100
#define H0STR 40     // halves; 80 B rows -> b128 A-frag reads 2-way (free)
#define H1STR 56     // halves; 112 B rows; cols 51..55 pad, col 50 = 1.0 (bias)
#define MROWS 176    // worst case: sum 16*ceil(c_t/16) = 176 rows
#define W1H_HALVES (16 * 50 * 32)     // 25600  (K 25 -> 32; col 25 = CT*b1)
#define W2H_HALVES (16 * 100 * 64)    // 102400 (K 50 -> 64; col 50 = CT*b2)
#define WS_DWORDS  ((W1H_HALVES + W2H_HALVES) / 2)   // 64000 dwords of fp16
#define W0C_FLOATS 800                // 16*25 float2 {CT*w0, CT*b0}
#define CT 2.8853900817779268f        // 2*log2(e); tanh(x)=1-2/(exp2(CT*x)+1)

typedef _Float16 half8 __attribute__((ext_vector_type(8)));  // 8 fp16 = 4 VGPRs
typedef _Float16 half4v __attribute__((ext_vector_type(4))); // 4 fp16 = 2 VGPRs
typedef _Float16 half2v __attribute__((ext_vector_type(2))); // 2 fp16 = 1 VGPR
typedef __attribute__((ext_vector_type(4))) float f32x4;

__device__ __forceinline__ float exp2_hw(float x) {
#if defined(__has_builtin)
#if __has_builtin(__builtin_amdgcn_exp2f)
    return __builtin_amdgcn_exp2f(x);        // raw v_exp_f32 (exp2 semantics)
#else
    return __expf(0.6931471805599453f * x);
#endif
#else
    return __expf(0.6931471805599453f * x);
#endif
}

// tanh(x) with PRE-SCALED argument y = CT*x (CT folded into weights/bias):
// tanh(x) = 1 - 2/(exp2(y)+1). exp2->add->rcp->fma.
__device__ __forceinline__ float tanh_pre(float y) {
    float e = exp2_hw(y);
    return 1.0f - 2.0f * __builtin_amdgcn_rcpf(e + 1.0f);
}

// Two f32 -> packed 2xf16 in ONE instruction (v_cvt_pkrtz_f16_f32).
// RTZ rounding: <=1 ulp different from RNE -- same error class as fp16 store.
__device__ __forceinline__ half2v pk_f16(float a, float b) {
#if defined(__has_builtin)
#if __has_builtin(__builtin_amdgcn_cvt_pkrtz)
    return __builtin_bit_cast(half2v, __builtin_amdgcn_cvt_pkrtz(a, b));
#else
    half2v r; r[0] = (_Float16)a; r[1] = (_Float16)b; return r;
#endif
#else
    half2v r; r[0] = (_Float16)a; r[1] = (_Float16)b; return r;
#endif
}

struct F3 { float x, y, z; };   // one dwordx3 load (4B-aligned)

// ---- one-shot (per launch) weight repack into d_ws ----------------------
// W1h[idx][o][k32]: k<25 = CT*W1, k==25 = CT*b1 (bias rides the MFMA via
// H0f col25 == 1.0), k>25 = 0.  W2h[idx][o][k64]: k<50 = CT*W2,
// k==50 = CT*b2 (H1f col50 == 1.0), k>50 = 0.  |CT*W| <= 0.6 -> fp16-safe.
// Appended: W0c[idx*25+o] = float2{CT*W0, CT*B0} (fused layer-0 table).
__global__ void cvt_kernel(const float* __restrict__ W0,
                           const float* __restrict__ B0,
                           const float* __restrict__ W1,
                           const float* __restrict__ B1,
                           const float* __restrict__ W2,
                           const float* __restrict__ B2,
                           unsigned int* __restrict__ ws) {
    const int i = blockIdx.x * 256 + threadIdx.x;   // dword index
    if (i >= WS_DWORDS + W0C_FLOATS) return;
    if (i >= WS_DWORDS) {                           // layer-0 float2 table
        const int j = i - WS_DWORDS;                // 0..799
        const int p = j >> 1;                       // idx*25+o
        const float v = (j & 1) ? B0[p] : W0[p];
        reinterpret_cast<float*>(ws)[i] = CT * v;
        return;
    }
    float v0, v1;
    if (i < W1H_HALVES / 2) {
        const int s = 2 * i;
        const int row = s >> 5, kk = s & 31;        // row = idx*50 + o
        const float* base = W1 + row * D0;
        v0 = (kk < D0) ? base[kk] : ((kk == D0) ? B1[row] : 0.f);
        v1 = (kk + 1 < D0) ? base[kk + 1] : ((kk + 1 == D0) ? B1[row] : 0.f);
    } else {
        const int s = 2 * i - W1H_HALVES;
        const int row = s >> 6, kk = s & 63;        // row = idx*100 + o
        const float* base = W2 + row * D1;
        v0 = (kk < D1) ? base[kk] : ((kk == D1) ? B2[row] : 0.f);
        v1 = (kk + 1 < D1) ? base[kk + 1] : ((kk + 1 == D1) ? B2[row] : 0.f);
    }
    union { _Float16 h[2]; unsigned int u; } cv;
    cv.h[0] = (_Float16)(CT * v0);                  // RNE, range-safe
    cv.h[1] = (_Float16)(CT * v1);
    ws[i] = cv.u;
}

__global__ __launch_bounds__(256, 1) void feat_kernel(
    const float* __restrict__ coords,
    const int*   __restrict__ types,
    const float2* __restrict__ W0c,
    const _Float16* __restrict__ W1h, const _Float16* __restrict__ W2h,
    float* __restrict__ out)
{
    // 19712 + 14080 + 1056 + 624 + 32 = 35504 B -> 4 blocks/CU, 16 waves
    __shared__ __attribute__((aligned(16))) _Float16 H1f[MROWS][H1STR];
    // H0f's last read is before the 2a->2b barrier; Ms is written only in 2b.
    __shared__ union __attribute__((aligned(16))) {
        _Float16 H0f[MROWS][H0STR];
        float    Ms[3][112];
    } u;
    // env_a as 3 fp16 planes; the b64 read IS the reduce-MFMA A-frag.
    __shared__ __attribute__((aligned(16))) _Float16 Eph[3][MROWS];
    // residual sums R[c][j] = sum_m E[c][m]*h1[m][j], built in 2a (via MFMA).
    __shared__ float Rt[3][52];
    __shared__ int cnt[2][4];           // per-wave type counts (waves 0,1)

    const int bn = blockIdx.x;    // b*128 + n
    const int b  = bn >> 7;
    const int n  = bn & 127;
    const int k  = threadIdx.x;   // 0..255
    const int wv = k >> 6;        // wave 0..3
    const int lq = (k >> 4) & 3;  // quad within wave
    const int ln = k & 15;
    const int lane = k & 63;
    const int tn  = types[n];

    // ---- ballot-based type counts + stable ranks.
    // Threads 128+i mirror thread i's neighbor: waves {0,2} and {1,3} have
    // identical lane<->neighbor maps, so ranks come free for both halves.
    int tj = -1, j0 = 0, jj = -1;
    if (k < NB) jj = k;
    else if (k >= 128 && k < 128 + NB) jj = k - 128;
    if (jj >= 0) { j0 = jj + (jj >= n ? 1 : 0); tj = types[j0]; }
    const unsigned long long bm0 = __ballot(tj == 0);
    const unsigned long long bm1 = __ballot(tj == 1);
    const unsigned long long bm2 = __ballot(tj == 2);
    const unsigned long long bm3 = __ballot(tj == 3);
    if (lane == 0 && wv < 2) {
        cnt[wv][0] = __popcll(bm0); cnt[wv][1] = __popcll(bm1);
        cnt[wv][2] = __popcll(bm2); cnt[wv][3] = __popcll(bm3);
    }
    int sameBefore = 0;
    if (jj >= 0) {
        const unsigned long long mym =
            (tj == 0) ? bm0 : (tj == 1) ? bm1 : (tj == 2) ? bm2 : bm3;
        sameBefore = __popcll(mym & ((1ULL << lane) - 1ULL));
    }
    __syncthreads();

    const int c0 = cnt[0][0] + cnt[1][0];
    const int c1 = cnt[0][1] + cnt[1][1];
    const int c2 = cnt[0][2] + cnt[1][2];
    const int c3 = cnt[0][3] + cnt[1][3];
    const int ps1 = (c0 + 15) & ~15;
    const int ps2 = ps1 + ((c1 + 15) & ~15);
    const int ps3 = ps2 + ((c2 + 15) & ~15);

    // ======== phase 1: geometry + layer 0, split across ALL 256 threads ====
    // A-half (k<128): Eph + h0[0..11] (3 uint2 stores, dwords 0..5).
    // B-half: h0[12..24] + col25=1.0 (bias lane) + K-pad (5 uint2 stores).
    // Layer-0 weights come fused from W0c: one b64 load + fmaf per neuron.
    if (jj >= 0) {
        const int idx = (tn << 2) | tj;
        const int pst = (tj == 0) ? 0 : (tj == 1) ? ps1 : (tj == 2) ? ps2 : ps3;
        const int pr  = pst + sameBefore + ((wv & 1) ? cnt[0][tj] : 0);

        const float cx = coords[(b * NATOM + n) * 3 + 0];
        const float cy = coords[(b * NATOM + n) * 3 + 1];
        const float cz = coords[(b * NATOM + n) * 3 + 2];
        const F3 cj = *reinterpret_cast<const F3*>(&coords[(b * NATOM + j0) * 3]);
        const float dx = cx - cj.x;
        const float dy = cy - cj.y;
        const float dz = cz - cj.z;
        const float d2   = dx * dx + dy * dy + dz * dz;
        const float inv  = rsqrtf(d2);         // 1/d (= env_r)
        const float inv2 = inv * inv;

        const float2* wb = W0c + idx * D0;     // {CT*w, CT*b} pairs
        uint2* dst2 = (uint2*)&u.H0f[pr][0];

        if (k < 128) {                         // A-half: Eph planes + h0[0..11]
            Eph[0][pr] = (_Float16)(dx * inv2);
            Eph[1][pr] = (_Float16)(dy * inv2);
            Eph[2][pr] = (_Float16)(dz * inv2);
            unsigned int dv[6];
            #pragma unroll
            for (int o = 0; o < 12; o += 2) {
                const float2 wc0 = wb[o];
                const float2 wc1 = wb[o + 1];
                union { half2v h; unsigned int v; } cv;
                cv.h = pk_f16(tanh_pre(fmaf(wc0.x, inv, wc0.y)),
                              tanh_pre(fmaf(wc1.x, inv, wc1.y)));
                dv[o >> 1] = cv.v;
            }
            uint2 s0; s0.x = dv[0]; s0.y = dv[1]; dst2[0] = s0;
            uint2 s1; s1.x = dv[2]; s1.y = dv[3]; dst2[1] = s1;
            uint2 s2; s2.x = dv[4]; s2.y = dv[5]; dst2[2] = s2;
        } else {                               // B-half: h0[12..24] + bias + pad
            unsigned int dv[7];
            #pragma unroll
            for (int q = 0; q < 6; ++q) {      // cols 12..23
                const float2 wc0 = wb[12 + 2 * q];
                const float2 wc1 = wb[13 + 2 * q];
                union { half2v h; unsigned int v; } cv;
                cv.h = pk_f16(tanh_pre(fmaf(wc0.x, inv, wc0.y)),
                              tanh_pre(fmaf(wc1.x, inv, wc1.y)));
                dv[q] = cv.v;
            }
            { const float2 wc = wb[24];        // col 24 + bias-1.0 @ col 25
              union { half2v h; unsigned int v; } cl;
              cl.h = pk_f16(tanh_pre(fmaf(wc.x, inv, wc.y)), 1.0f);
              dv[6] = cl.v; }
            uint2 s3; s3.x = dv[0]; s3.y = dv[1]; dst2[3] = s3;
            uint2 s4; s4.x = dv[2]; s4.y = dv[3]; dst2[4] = s4;
            uint2 s5; s5.x = dv[4]; s5.y = dv[5]; dst2[5] = s5;
            uint2 s6; s6.x = dv[6]; s6.y = 0u;   dst2[6] = s6;   // cols 24..27
            uint2 s7; s7.x = 0u;    s7.y = 0u;   dst2[7] = s7;   // cols 28..31
        }
    }
    // ---- pad-ROW zeroing: <=49 rows, spare B-side threads. Zero h0 K-range
    // (incl col25 -> pad-row z1 = 0 -> h1 = 0) + Eph planes (Mc/R mask).
    if (k >= 128 && k < 255) {
        const int i = k - 128;
        const int p0 = ((c0 + 15) & ~15) - c0;
        const int p1 = ((c1 + 15) & ~15) - c1;
        const int p2 = ((c2 + 15) & ~15) - c2;
        const int p3 = ((c3 + 15) & ~15) - c3;
        int row = -1;
        if (i < p0)                row = c0 + i;
        else if (i < p0 + p1)      row = ps1 + c1 + (i - p0);
        else if (i < p0 + p1 + p2) row = ps2 + c2 + (i - p0 - p1);
        else if (i < p0 + p1 + p2 + p3)
                                   row = ps3 + c3 + (i - p0 - p1 - p2);
        if (row >= 0) {
            uint2* pz = (uint2*)&u.H0f[row][0];
            const uint2 z2 = {0u, 0u};
            #pragma unroll
            for (int q = 0; q < 8; ++q) pz[q] = z2;
            Eph[0][row] = (_Float16)0.f;
            Eph[1][row] = (_Float16)0.f;
            Eph[2][row] = (_Float16)0.f;
        }
    }
    __syncthreads();

    // ======== phase 2a: layer 1 via MFMA (25+bias -> 50), K padded to 32 ===
    // Bias comes via K-col 25 (H0f==1.0, W1h==CT*b1): accumulator starts 0.
    // Residual table R[c][o1] = sum_m E[c][m]*h1[m][o1] built ON THE MFMA
    // PIPE: 16x16x16 with A = E (rows c = 0..2, rows >=3 don't-care), B = the
    // packed h1 quad (lane already holds B[k=lq*4+j][col=ln] exactly).
    {
        const int o1   = wv * 16 + ln;         // 0..63
        const bool ov1 = (o1 < D1);
        const bool st1 = (o1 < H1STR);         // only cols 0..55 exist
        const int o1c  = ov1 ? o1 : 0;         // clamp: pad lanes load row 0
        const int rres1 = ((o1 < D0) ? o1 : (o1 - D0)) & 31;  // in-row clamp
        const _Float16 padv = (o1 == D1) ? (_Float16)1.0f : (_Float16)0.f;
        const int cpl = (ln < 3) ? ln : 2;     // E-plane; rows>=3 of D2 unread
        f32x4 d2r = {0.f, 0.f, 0.f, 0.f};      // R accumulator (rows = c)
        #pragma unroll
        for (int t = 0; t < 4; ++t) {
            const int cnt_t = (t == 0) ? c0 : (t == 1) ? c1 : (t == 2) ? c2 : c3;
            if (cnt_t == 0) continue;
            const int ps  = (t == 0) ? 0 : (t == 1) ? ps1 : (t == 2) ? ps2 : ps3;
            const int idx = (tn << 2) | t;
            const half8 bf =
                *(const half8*)(W1h + (idx * 50 + o1c) * 32 + lq * 8);
            const int mtiles = (cnt_t + 15) >> 4;
            for (int mt = 0; mt < mtiles; ++mt) {
                const int mb = ps + mt * 16;
                const half8 af = *(const half8*)(&u.H0f[mb + ln][lq * 8]);
                f32x4 d = {0.f, 0.f, 0.f, 0.f};        // bias rides K-col 25
                d = __builtin_amdgcn_mfma_f32_16x16x32_f16(af, bf, d, 0, 0, 0);
                const int mq = mb + lq * 4;
                const half4v ea = *(const half4v*)&Eph[cpl][mq]; // b64, no cvt
                // packed tanh (2 pkrtz) + packed residual add (2 pk_add)
                half2v t01 = pk_f16(tanh_pre(d[0]), tanh_pre(d[1]));
                half2v t23 = pk_f16(tanh_pre(d[2]), tanh_pre(d[3]));
                half2v q01; q01[0] = u.H0f[mq + 0][rres1];
                            q01[1] = u.H0f[mq + 1][rres1];
                half2v q23; q23[0] = u.H0f[mq + 2][rres1];
                            q23[1] = u.H0f[mq + 3][rres1];
                t01 = t01 + q01;               // v_pk_add_f16
                t23 = t23 + q23;
                half4v gb;
                gb[0] = t01[0]; gb[1] = t01[1];
                gb[2] = t23[0]; gb[3] = t23[1];
                if (st1) {
                    H1f[mq + 0][o1] = ov1 ? t01[0] : padv;
                    H1f[mq + 1][o1] = ov1 ? t01[1] : padv;
                    H1f[mq + 2][o1] = ov1 ? t23[0] : padv;
                    H1f[mq + 3][o1] = ov1 ? t23[1] : padv;
                }
                d2r = __builtin_amdgcn_mfma_f32_16x16x16f16(ea, gb, d2r, 0, 0, 0);
            }
        }
        if (lq == 0 && o1 < D1) {              // D2 rows 0..2 (= c) live at lq==0
            Rt[0][o1] = d2r[0]; Rt[1][o1] = d2r[1]; Rt[2][o1] = d2r[2];
        }
    }
    __syncthreads();
    // ---- from here on, u is Ms; H0f is dead (all reads were pre-barrier)

    // ======== phase 2b: layer 2 via MFMA (50+bias -> 100) + MFMA M-reduce ==
    // Single pass over m-tiles; wave wv computes BOTH its groups (wv, wv+4)
    // per tile so the af/Eph reads are shared. Bias via K-col 50. The E-
    // weighted reduction Mc[c][o] = sum_m E[c][m]*g[m][o] runs on the MFMA
    // pipe (16x16x16, packed tanh output as B) -- no fma chains, no shuffles.
    {
        const bool has1 = (wv < 3);             // group wv+4 exists (4..6)
        const int oA  = wv * 16 + ln;           // group-0 neuron (<64, real)
        const int oB  = (wv + 4) * 16 + ln;     // group-1 neuron (may pad)
        const int ocB = (oB < D2) ? oB : (D2 - 1);
        const int rrA = (oA >= D1) ? (oA - D1) : oA;    // residual columns
        const int rrB = (ocB >= D1) ? (ocB - D1) : ocB;
        const int off1 = (lq == 3) ? 32 : (32 + lq * 8); // lq=3 K-rows of W2h=0
        const int cpl = (ln < 3) ? ln : 2;
        f32x4 d2A = {0.f, 0.f, 0.f, 0.f};       // Mc accumulators (rows = c)
        f32x4 d2B = {0.f, 0.f, 0.f, 0.f};
        #pragma unroll
        for (int t = 0; t < 4; ++t) {
            const int cnt_t = (t == 0) ? c0 : (t == 1) ? c1 : (t == 2) ? c2 : c3;
            if (cnt_t == 0) continue;
            const int ps  = (t == 0) ? 0 : (t == 1) ? ps1 : (t == 2) ? ps2 : ps3;
            const int idx = (tn << 2) | t;
            const _Float16* wrA = W2h + (idx * 100 + oA) * 64;
            const half8 bfA0 = *(const half8*)(wrA + lq * 8);
            const half8 bfA1 = *(const half8*)(wrA + 32 + lq * 8);
            const _Float16* wrB = W2h + (idx * 100 + ocB) * 64;
            const half8 bfB0 = *(const half8*)(wrB + lq * 8);
            const half8 bfB1 = *(const half8*)(wrB + 32 + lq * 8);
            const int mtiles = (cnt_t + 15) >> 4;
            for (int mt = 0; mt < mtiles; ++mt) {
                const int mb = ps + mt * 16;
                const _Float16* arow = &H1f[mb + ln][0];
                const half8 af0 = *(const half8*)(arow + lq * 8);
                const half8 af1 = *(const half8*)(arow + off1);
                const int mq = mb + lq * 4;
                const half4v ea = *(const half4v*)&Eph[cpl][mq]; // b64, no cvt
                {
                    f32x4 d = {0.f, 0.f, 0.f, 0.f};    // bias rides K-col 50
                    d = __builtin_amdgcn_mfma_f32_16x16x32_f16(af0, bfA0, d, 0, 0, 0);
                    d = __builtin_amdgcn_mfma_f32_16x16x32_f16(af1, bfA1, d, 0, 0, 0);
                    half2v a01 = pk_f16(tanh_pre(d[0]), tanh_pre(d[1]));
                    half2v a23 = pk_f16(tanh_pre(d[2]), tanh_pre(d[3]));
                    half4v ga;
                    ga[0] = a01[0]; ga[1] = a01[1];
                    ga[2] = a23[0]; ga[3] = a23[1];
                    d2A = __builtin_amdgcn_mfma_f32_16x16x16f16(ea, ga, d2A, 0, 0, 0);
                }
                if (has1) {
                    f32x4 d = {0.f, 0.f, 0.f, 0.f};
                    d = __builtin_amdgcn_mfma_f32_16x16x32_f16(af0, bfB0, d, 0, 0, 0);
                    d = __builtin_amdgcn_mfma_f32_16x16x32_f16(af1, bfB1, d, 0, 0, 0);
                    half2v b01 = pk_f16(tanh_pre(d[0]), tanh_pre(d[1]));
                    half2v b23 = pk_f16(tanh_pre(d[2]), tanh_pre(d[3]));
                    half4v gb2;
                    gb2[0] = b01[0]; gb2[1] = b01[1];
                    gb2[2] = b23[0]; gb2[3] = b23[1];
                    d2B = __builtin_amdgcn_mfma_f32_16x16x16f16(ea, gb2, d2B, 0, 0, 0);
                }
            }
        }
        // D2 rows 0..2 (= c) live in lq==0 lanes; residual added via Rt.
        if (lq == 0) {                          // oA <= 63 < 100: always real
            u.Ms[0][oA] = d2A[0] + Rt[0][rrA];
            u.Ms[1][oA] = d2A[1] + Rt[1][rrA];
            u.Ms[2][oA] = d2A[2] + Rt[2][rrA];
            if (has1 && oB < D2) {
                u.Ms[0][oB] = d2B[0] + Rt[0][rrB];
                u.Ms[1][oB] = d2B[1] + Rt[1][rrB];
                u.Ms[2][oB] = d2B[2] + Rt[2][rrB];
            }
        }
    }
    __syncthreads();

    // ======== phase 3: out[m][a] = sum_c M[c][m] * M[c][a], a < 4 ==========
    if (k < D2) {
        const float m0 = u.Ms[0][k], m1 = u.Ms[1][k], m2 = u.Ms[2][k];
        float4 o4;
        o4.x = m0 * u.Ms[0][0] + m1 * u.Ms[1][0] + m2 * u.Ms[2][0];
        o4.y = m0 * u.Ms[0][1] + m1 * u.Ms[1][1] + m2 * u.Ms[2][1];
        o4.z = m0 * u.Ms[0][2] + m1 * u.Ms[1][2] + m2 * u.Ms[2][2];
        o4.w = m0 * u.Ms[0][3] + m1 * u.Ms[1][3] + m2 * u.Ms[2][3];
        reinterpret_cast<float4*>(out)[bn * D2 + k] = o4;   // 16B-aligned
    }
}

extern "C" void kernel_launch(void* const* d_in, const int* in_sizes, int n_in,
                              void* d_out, int out_size, void* d_ws, size_t ws_size,
                              hipStream_t stream) {
    (void)in_sizes; (void)n_in; (void)out_size; (void)ws_size;
    const float* coords = (const float*)d_in[0];
    const int*   types  = (const int*)  d_in[1];
    const float* W0 = (const float*)d_in[2];
    const float* B0 = (const float*)d_in[3];
    const float* W1 = (const float*)d_in[4];
    const float* B1 = (const float*)d_in[5];
    const float* W2 = (const float*)d_in[6];
    const float* B2 = (const float*)d_in[7];
    float* out = (float*)d_out;

    unsigned int* ws_u = (unsigned int*)d_ws;
    _Float16* W1h = (_Float16*)d_ws;                 // 25600 halves (CT-scaled)
    _Float16* W2h = (_Float16*)d_ws + W1H_HALVES;    // 102400 halves (CT-scaled)
    const float2* W0c = (const float2*)(ws_u + WS_DWORDS);  // 400 float2

    const int total = WS_DWORDS + W0C_FLOATS;        // 64800 dwords
    cvt_kernel<<<(total + 255) / 256, 256, 0, stream>>>(
        W0, B0, W1, B1, W2, B2, ws_u);

    feat_kernel<<<64 * NATOM, 256, 0, stream>>>(
        coords, types, W0c, W1h, W2h, out);
}